// Round 1
// baseline (1596.055 us; speedup 1.0000x reference)
//
#include <hip/hip_runtime.h>

#define HW 1024
#define CCH 256
#define NBATCH 4

// ws layout (floats):
//   xn: [4][256][1024]        off 0         1,048,576
//   A : [4][1024][1024]       off 1048576   4,194,304
//   z : [16][1024][1024]      off 5242880  16,777,216   (per-batch reuse)
//   xc: [1024][1024]          off 22020096  1,048,576   (per-batch reuse)
// total 23,068,672 floats = 92.3 MB

__global__ __launch_bounds__(256) void norm_kernel(const float* __restrict__ x,
                                                   float* __restrict__ xn) {
    int b = blockIdx.y;
    int p = blockIdx.x * 256 + threadIdx.x;
    const float* xb = x + (size_t)b * CCH * HW;
    float* xnb = xn + (size_t)b * CCH * HW;
    float ss = 0.f;
#pragma unroll 8
    for (int c = 0; c < CCH; ++c) { float v = xb[c * HW + p]; ss += v * v; }
    float inv = 1.0f / fmaxf(sqrtf(ss), 1e-12f);
#pragma unroll 8
    for (int c = 0; c < CCH; ++c) xnb[c * HW + p] = xb[c * HW + p] * inv;
}

// A[b][p][m] = g(p,m) * sum_c xn[b][c][p] * xn[b][c][m]
__global__ __launch_bounds__(256) void aff_kernel(const float* __restrict__ xn,
                                                  float* __restrict__ Aout) {
    int b = blockIdx.z;
    int p0 = blockIdx.y * 64;
    int m0 = blockIdx.x * 64;
    const float* X = xn + (size_t)b * CCH * HW;
    __shared__ float As[16][64];
    __shared__ float Bs[16][64];
    int tid = threadIdx.x;
    int ty = tid >> 4, tx = tid & 15;
    float acc[4][4] = {};
    for (int kk = 0; kk < CCH; kk += 16) {
        int lr = tid >> 4;
        int lc4 = (tid & 15) * 4;
        *(float4*)&As[lr][lc4] = *(const float4*)&X[(size_t)(kk + lr) * HW + p0 + lc4];
        *(float4*)&Bs[lr][lc4] = *(const float4*)&X[(size_t)(kk + lr) * HW + m0 + lc4];
        __syncthreads();
#pragma unroll
        for (int k = 0; k < 16; ++k) {
            float4 av = *(float4*)&As[k][ty * 4];
            float4 bv = *(float4*)&Bs[k][tx * 4];
            float aa[4] = {av.x, av.y, av.z, av.w};
            float bb[4] = {bv.x, bv.y, bv.z, bv.w};
#pragma unroll
            for (int i = 0; i < 4; ++i)
#pragma unroll
                for (int j = 0; j < 4; ++j) acc[i][j] += aa[i] * bb[j];
        }
        __syncthreads();
    }
#pragma unroll
    for (int i = 0; i < 4; ++i) {
        int p = p0 + ty * 4 + i;
        int prr = p >> 5, pcc = p & 31;
        float res[4];
#pragma unroll
        for (int j = 0; j < 4; ++j) {
            int m = m0 + tx * 4 + j;
            int dr = (m >> 5) - prr;
            int dc = (m & 31) - pcc;
            float gg = 1.0f - __expf(-(float)(dr * dr + dc * dc) * 0.1953125f);
            res[j] = acc[i][j] * gg;
        }
        *(float4*)&Aout[((size_t)b * HW + p) * HW + m0 + tx * 4] =
            make_float4(res[0], res[1], res[2], res[3]);
    }
}

// conv1: z[ch][P][Q] = sum_{i,j,u,v} w1[ch,0,i,j,u,v] * A[b][P+(i-1,j-1)][Q+(u-1,v-1)] + bias1(r1,ch)
__global__ __launch_bounds__(256) void conv1_kernel(const float* __restrict__ A,
                                                    const float* __restrict__ w1,
                                                    const float* __restrict__ b1,
                                                    float* __restrict__ z, int b) {
    __shared__ float At[9][34 * 34];
    __shared__ float w1s[1296];  // transposed: [tap(81)][ch(16)]
    int tid = threadIdx.x;
    int P = blockIdx.x;
    int r1 = P >> 5, c1 = P & 31;

    for (int i = tid; i < 1296; i += 256) {
        int ch = i / 81;
        int off = i - ch * 81;
        w1s[off * 16 + ch] = w1[i];
    }
    for (int i = tid; i < 9 * 34 * 34; i += 256) ((float*)At)[i] = 0.f;
    __syncthreads();
    for (int nb = 0; nb < 9; ++nb) {
        int r1p = r1 + nb / 3 - 1, c1p = c1 + nb % 3 - 1;
        if ((unsigned)r1p < 32u && (unsigned)c1p < 32u) {
            const float* src = A + ((size_t)b * HW + (r1p * 32 + c1p)) * HW;
            for (int i = tid; i < 1024; i += 256)
                At[nb][(i >> 5) * 34 + (i & 31) + 35] = src[i];
        }
    }
    __syncthreads();

    int c2 = tid & 31, r2b = tid >> 5;  // pixels q = tid + 256*s, s=0..3
    float acc[16][4] = {};
    for (int nb = 0; nb < 9; ++nb) {
        const float* Ap = At[nb];
        int wb = (nb / 3) * 27 + (nb % 3) * 9;
#pragma unroll
        for (int u = 0; u < 3; ++u)
#pragma unroll
            for (int v = 0; v < 3; ++v) {
                int off = wb + u * 3 + v;
                float a0 = Ap[(r2b + u) * 34 + c2 + v];
                float a1 = Ap[(r2b + 8 + u) * 34 + c2 + v];
                float a2 = Ap[(r2b + 16 + u) * 34 + c2 + v];
                float a3 = Ap[(r2b + 24 + u) * 34 + c2 + v];
#pragma unroll
                for (int cg = 0; cg < 4; ++cg) {
                    float4 wv = *(const float4*)&w1s[off * 16 + cg * 4];
                    float wa[4] = {wv.x, wv.y, wv.z, wv.w};
#pragma unroll
                    for (int cc = 0; cc < 4; ++cc) {
                        int ch = cg * 4 + cc;
                        acc[ch][0] += wa[cc] * a0;
                        acc[ch][1] += wa[cc] * a1;
                        acc[ch][2] += wa[cc] * a2;
                        acc[ch][3] += wa[cc] * a3;
                    }
                }
            }
    }

#pragma unroll
    for (int ch = 0; ch < 16; ++ch) {
        float bias = b1[16 + ch];
        if (r1 >= 1) bias += b1[ch];
        if (r1 <= 30) bias += b1[32 + ch];
        float* zp = z + ((size_t)ch * HW + P) * HW;
        zp[tid] = acc[ch][0] + bias;
        zp[tid + 256] = acc[ch][1] + bias;
        zp[tid + 512] = acc[ch][2] + bias;
        zp[tid + 768] = acc[ch][3] + bias;
    }
}

#define PSTR 101
// conv2: xc[P][Q] = sum_{ch,i,j,u,v} w2[0,ch,i,j,u,v] * z[ch][P+..][Q+..] + bias2(r1)
__global__ __launch_bounds__(256) void conv2_kernel(const float* __restrict__ z,
                                                    const float* __restrict__ w2,
                                                    const float* __restrict__ b2,
                                                    float* __restrict__ xc) {
    __shared__ float zl[100 * PSTR + 4];
    __shared__ float w2s[1296];
    int tid = threadIdx.x;
    int pt = blockIdx.y, qt = blockIdx.x;
    int p0r = (pt >> 2) * 8, p0c = (pt & 3) * 8;
    int q0r = (qt >> 2) * 8, q0c = (qt & 3) * 8;
    for (int i = tid; i < 1296; i += 256) w2s[i] = w2[i];

    int pl = tid & 63;
    int pr = pl >> 3, pc = pl & 7;
    int qg = tid >> 6;  // owns q rows {qg*2, qg*2+1} x 8 cols
    float acc[16] = {};

    for (int ch = 0; ch < 16; ++ch) {
        __syncthreads();  // protect zl from previous iter readers
        for (int i = tid; i < 10000; i += 256) {
            int a = i / 1000;
            int r = i - a * 1000;
            int bb = r / 100; r -= bb * 100;
            int cq = r / 10;
            int dq = r - cq * 10;
            int gpr = p0r + a - 1, gpc = p0c + bb - 1;
            int gqr = q0r + cq - 1, gqc = q0c + dq - 1;
            float v = 0.f;
            if ((unsigned)gpr < 32u && (unsigned)gpc < 32u && (unsigned)gqr < 32u &&
                (unsigned)gqc < 32u)
                v = z[((size_t)ch * HW + (gpr * 32 + gpc)) * HW + gqr * 32 + gqc];
            zl[(a * 10 + bb) * PSTR + cq * 10 + dq] = v;
        }
        __syncthreads();
#pragma unroll
        for (int dpr = 0; dpr < 3; ++dpr)
#pragma unroll
            for (int dpc = 0; dpc < 3; ++dpc) {
                const float* zb = &zl[((pr + dpr) * 10 + (pc + dpc)) * PSTR + (qg * 2) * 10];
                float rb[4][10];
#pragma unroll
                for (int r = 0; r < 4; ++r)
#pragma unroll
                    for (int j = 0; j < 10; ++j) rb[r][j] = zb[r * 10 + j];
                int wb = ch * 81 + dpr * 27 + dpc * 9;
                float w9[9];
#pragma unroll
                for (int t = 0; t < 9; ++t) w9[t] = w2s[wb + t];
#pragma unroll
                for (int u = 0; u < 3; ++u)
#pragma unroll
                    for (int qrr = 0; qrr < 2; ++qrr)
#pragma unroll
                        for (int v = 0; v < 3; ++v)
#pragma unroll
                            for (int qc = 0; qc < 8; ++qc)
                                acc[qrr * 8 + qc] += w9[u * 3 + v] * rb[qrr + u][qc + v];
            }
    }

    int r1 = p0r + pr;
    float bias = b2[1] + (r1 >= 1 ? b2[0] : 0.f) + (r1 <= 30 ? b2[2] : 0.f);
    __syncthreads();
    float* sm = zl;  // reuse as [64][65] transpose buffer (4160 floats)
#pragma unroll
    for (int i = 0; i < 16; ++i) sm[pl * 65 + qg * 16 + i] = acc[i] + bias;
    __syncthreads();
    for (int i = tid; i < 4096; i += 256) {
        int lp = i >> 6;
        int ql = i & 63;
        int gp = (p0r + (lp >> 3)) * 32 + p0c + (lp & 7);
        int gq = (q0r + (ql >> 3)) * 32 + q0c + (ql & 7);
        xc[(size_t)gp * HW + gq] = sm[lp * 65 + ql];
    }
}

__global__ __launch_bounds__(256) void topk_kernel(const float* __restrict__ xc,
                                                   float* __restrict__ out, int b) {
    int q = blockIdx.x * 256 + threadIdx.x;
    float t0 = -1e30f, t1 = -1e30f, t2 = -1e30f;
    for (int p = 0; p < HW; ++p) {
        float v = xc[(size_t)p * HW + q];
        float n0 = fminf(t0, v);
        t0 = fmaxf(t0, v);
        float n1 = fminf(t1, n0);
        t1 = fmaxf(t1, n0);
        t2 = fmaxf(t2, n1);
    }
    float* ob = out + (size_t)b * 3 * HW;
    ob[q] = t0;
    ob[HW + q] = t1;
    ob[2 * HW + q] = t2;
}

extern "C" void kernel_launch(void* const* d_in, const int* in_sizes, int n_in,
                              void* d_out, int out_size, void* d_ws, size_t ws_size,
                              hipStream_t stream) {
    const float* x = (const float*)d_in[0];
    const float* w1 = (const float*)d_in[1];
    const float* b1 = (const float*)d_in[2];
    const float* w2 = (const float*)d_in[3];
    const float* b2 = (const float*)d_in[4];
    float* out = (float*)d_out;
    float* ws = (float*)d_ws;

    float* xn = ws;
    float* A = ws + 1048576;
    float* z = ws + 5242880;
    float* xc = ws + 22020096;

    norm_kernel<<<dim3(4, NBATCH), 256, 0, stream>>>(x, xn);
    aff_kernel<<<dim3(16, 16, NBATCH), 256, 0, stream>>>(xn, A);
    for (int b = 0; b < NBATCH; ++b) {
        conv1_kernel<<<1024, 256, 0, stream>>>(A, w1, b1, z, b);
        conv2_kernel<<<dim3(16, 16), 256, 0, stream>>>(z, w2, b2, xc);
        topk_kernel<<<4, 256, 0, stream>>>(xc, out, b);
    }
}

// Round 2
// 1580.186 us; speedup vs baseline: 1.0100x; 1.0100x over previous
//
#include <hip/hip_runtime.h>

#define HW 1024
#define CCH 256
#define NBATCH 4

// ws layout (floats):
//   xn: [4][256][1024]        off 0         1,048,576
//   A : [4][1024][1024]       off 1048576   4,194,304
//   z : [16][1024][1024]      off 5242880  16,777,216   (per-batch reuse; topk
//                                                        partials also live here)
//   xc: [1024][1024]          off 22020096  1,048,576   (per-batch reuse)

__global__ __launch_bounds__(256) void norm_kernel(const float* __restrict__ x,
                                                   float* __restrict__ xn) {
    int b = blockIdx.y;
    int p = blockIdx.x * 256 + threadIdx.x;
    const float* xb = x + (size_t)b * CCH * HW;
    float* xnb = xn + (size_t)b * CCH * HW;
    float ss = 0.f;
#pragma unroll 8
    for (int c = 0; c < CCH; ++c) { float v = xb[c * HW + p]; ss += v * v; }
    float inv = 1.0f / fmaxf(sqrtf(ss), 1e-12f);
#pragma unroll 8
    for (int c = 0; c < CCH; ++c) xnb[c * HW + p] = xb[c * HW + p] * inv;
}

// A[b][p][m] = g(p,m) * sum_c xn[b][c][p] * xn[b][c][m]
__global__ __launch_bounds__(256) void aff_kernel(const float* __restrict__ xn,
                                                  float* __restrict__ Aout) {
    int b = blockIdx.z;
    int p0 = blockIdx.y * 64;
    int m0 = blockIdx.x * 64;
    const float* X = xn + (size_t)b * CCH * HW;
    __shared__ float As[16][64];
    __shared__ float Bs[16][64];
    int tid = threadIdx.x;
    int ty = tid >> 4, tx = tid & 15;
    float acc[4][4] = {};
    for (int kk = 0; kk < CCH; kk += 16) {
        int lr = tid >> 4;
        int lc4 = (tid & 15) * 4;
        *(float4*)&As[lr][lc4] = *(const float4*)&X[(size_t)(kk + lr) * HW + p0 + lc4];
        *(float4*)&Bs[lr][lc4] = *(const float4*)&X[(size_t)(kk + lr) * HW + m0 + lc4];
        __syncthreads();
#pragma unroll
        for (int k = 0; k < 16; ++k) {
            float4 av = *(float4*)&As[k][ty * 4];
            float4 bv = *(float4*)&Bs[k][tx * 4];
            float aa[4] = {av.x, av.y, av.z, av.w};
            float bb[4] = {bv.x, bv.y, bv.z, bv.w};
#pragma unroll
            for (int i = 0; i < 4; ++i)
#pragma unroll
                for (int j = 0; j < 4; ++j) acc[i][j] += aa[i] * bb[j];
        }
        __syncthreads();
    }
#pragma unroll
    for (int i = 0; i < 4; ++i) {
        int p = p0 + ty * 4 + i;
        int prr = p >> 5, pcc = p & 31;
        float res[4];
#pragma unroll
        for (int j = 0; j < 4; ++j) {
            int m = m0 + tx * 4 + j;
            int dr = (m >> 5) - prr;
            int dc = (m & 31) - pcc;
            float gg = 1.0f - __expf(-(float)(dr * dr + dc * dc) * 0.1953125f);
            res[j] = acc[i][j] * gg;
        }
        *(float4*)&Aout[((size_t)b * HW + p) * HW + m0 + tx * 4] =
            make_float4(res[0], res[1], res[2], res[3]);
    }
}

// conv1: z[ch][P][Q] = sum_{i,j,u,v} w1[ch,0,i,j,u,v] * A[b][P+(i-1,j-1)][Q+(u-1,v-1)]
//                      + bias1(r1,ch).   512 threads: 2 Q-pixels x 16 ch each.
__global__ __launch_bounds__(512) void conv1_kernel(const float* __restrict__ A,
                                                    const float* __restrict__ w1,
                                                    const float* __restrict__ b1,
                                                    float* __restrict__ z, int b) {
    __shared__ float At[9][34 * 34];
    __shared__ float w1s[1296];  // transposed: [tap(81)][ch(16)]
    int tid = threadIdx.x;
    int P = blockIdx.x;
    int r1 = P >> 5, c1 = P & 31;

    for (int i = tid; i < 1296; i += 512) {
        int ch = i / 81;
        int off = i - ch * 81;
        w1s[off * 16 + ch] = w1[i];
    }
    for (int i = tid; i < 9 * 34 * 34; i += 512) ((float*)At)[i] = 0.f;
    __syncthreads();
    for (int nb = 0; nb < 9; ++nb) {
        int r1p = r1 + nb / 3 - 1, c1p = c1 + nb % 3 - 1;
        if ((unsigned)r1p < 32u && (unsigned)c1p < 32u) {
            const float* src = A + ((size_t)b * HW + (r1p * 32 + c1p)) * HW;
            for (int i = tid; i < 1024; i += 512)
                At[nb][(i >> 5) * 34 + (i & 31) + 35] = src[i];
        }
    }
    __syncthreads();

    int c2 = tid & 31, r2g = tid >> 5;  // rows r2g and r2g+16
    float acc[16][2] = {};
    for (int nb = 0; nb < 9; ++nb) {
        const float* Ap = At[nb];
        int wb = (nb / 3) * 27 + (nb % 3) * 9;
#pragma unroll
        for (int u = 0; u < 3; ++u)
#pragma unroll
            for (int v = 0; v < 3; ++v) {
                int off = wb + u * 3 + v;
                float a0 = Ap[(r2g + u) * 34 + c2 + v];
                float a1 = Ap[(r2g + 16 + u) * 34 + c2 + v];
#pragma unroll
                for (int cg = 0; cg < 4; ++cg) {
                    float4 wv = *(const float4*)&w1s[off * 16 + cg * 4];
                    float wa[4] = {wv.x, wv.y, wv.z, wv.w};
#pragma unroll
                    for (int cc = 0; cc < 4; ++cc) {
                        acc[cg * 4 + cc][0] += wa[cc] * a0;
                        acc[cg * 4 + cc][1] += wa[cc] * a1;
                    }
                }
            }
    }

#pragma unroll
    for (int ch = 0; ch < 16; ++ch) {
        float bias = b1[16 + ch];
        if (r1 >= 1) bias += b1[ch];
        if (r1 <= 30) bias += b1[32 + ch];
        float* zp = z + ((size_t)ch * HW + P) * HW;
        zp[tid] = acc[ch][0] + bias;
        zp[tid + 512] = acc[ch][1] + bias;
    }
}

// conv2: block per P. Stage 9 neighbor z-images (per channel) as 34x35-stride
// padded halos; each thread computes a 4-wide Q strip.
#define HSTR 35
#define HSZ (34 * HSTR)
__global__ __launch_bounds__(256) void conv2_kernel(const float* __restrict__ z,
                                                    const float* __restrict__ w2,
                                                    const float* __restrict__ b2,
                                                    float* __restrict__ xc) {
    __shared__ float At[9 * HSZ];
    __shared__ float w2s[1296];
    int tid = threadIdx.x;
    int P = blockIdx.x;
    int r1 = P >> 5, c1 = P & 31;

    for (int i = tid; i < 1296; i += 256) w2s[i] = w2[i];
    for (int i = tid; i < 9 * HSZ; i += 256) At[i] = 0.f;

    int nboff[9];
    unsigned vmask = 0;
#pragma unroll
    for (int nb = 0; nb < 9; ++nb) {
        int r1p = r1 + nb / 3 - 1, c1p = c1 + nb % 3 - 1;
        nboff[nb] = r1p * 32 + c1p;
        if ((unsigned)r1p < 32u && (unsigned)c1p < 32u) vmask |= 1u << nb;
    }

    int r = tid >> 3;          // output q-row 0..31
    int c0 = (tid & 7) * 4;    // output q-col base
    float acc[4] = {};

    for (int ch = 0; ch < 16; ++ch) {
        __syncthreads();  // previous compute done before overwrite
#pragma unroll
        for (int nb = 0; nb < 9; ++nb) {
            if (!((vmask >> nb) & 1)) continue;
            const float* src = z + ((size_t)ch * HW + nboff[nb]) * HW;
            float* dst = &At[nb * HSZ];
            for (int i = tid; i < 1024; i += 256)
                dst[((i >> 5) + 1) * HSTR + (i & 31) + 1] = src[i];
        }
        __syncthreads();
#pragma unroll
        for (int nb = 0; nb < 9; ++nb) {
            if (!((vmask >> nb) & 1)) continue;
            const float* Ap = &At[nb * HSZ];
            const float* wp = &w2s[ch * 81 + nb * 9];
#pragma unroll
            for (int u = 0; u < 3; ++u) {
                const float* rp = &Ap[(r + u) * HSTR + c0];
                float rv[6];
#pragma unroll
                for (int m = 0; m < 6; ++m) rv[m] = rp[m];
#pragma unroll
                for (int v = 0; v < 3; ++v) {
                    float w = wp[u * 3 + v];
#pragma unroll
                    for (int k = 0; k < 4; ++k) acc[k] += w * rv[k + v];
                }
            }
        }
    }

    float bias = b2[1] + (r1 >= 1 ? b2[0] : 0.f) + (r1 <= 30 ? b2[2] : 0.f);
    float4 res = make_float4(acc[0] + bias, acc[1] + bias, acc[2] + bias, acc[3] + bias);
    *(float4*)&xc[(size_t)P * HW + r * 32 + c0] = res;
}

__device__ __forceinline__ void top3_push(float v, float& t0, float& t1, float& t2) {
    float n0 = fminf(t0, v);
    t0 = fmaxf(t0, v);
    float n1 = fminf(t1, n0);
    t1 = fmaxf(t1, n0);
    t2 = fmaxf(t2, n1);
}

// stage 1: block (qc, pc): top3 over 128 P-rows for 256 q columns
__global__ __launch_bounds__(256) void topk1_kernel(const float* __restrict__ xc,
                                                    float* __restrict__ part) {
    int q = blockIdx.x * 256 + threadIdx.x;
    int pc = blockIdx.y;
    float t0 = -1e30f, t1 = -1e30f, t2 = -1e30f;
    for (int p = pc * 128; p < pc * 128 + 128; ++p)
        top3_push(xc[(size_t)p * HW + q], t0, t1, t2);
    part[(size_t)(pc * 3 + 0) * HW + q] = t0;
    part[(size_t)(pc * 3 + 1) * HW + q] = t1;
    part[(size_t)(pc * 3 + 2) * HW + q] = t2;
}

__global__ __launch_bounds__(256) void topk2_kernel(const float* __restrict__ part,
                                                    float* __restrict__ out, int b) {
    int q = blockIdx.x * 256 + threadIdx.x;
    float t0 = -1e30f, t1 = -1e30f, t2 = -1e30f;
    for (int k = 0; k < 24; ++k) top3_push(part[(size_t)k * HW + q], t0, t1, t2);
    float* ob = out + (size_t)b * 3 * HW;
    ob[q] = t0;
    ob[HW + q] = t1;
    ob[2 * HW + q] = t2;
}

extern "C" void kernel_launch(void* const* d_in, const int* in_sizes, int n_in,
                              void* d_out, int out_size, void* d_ws, size_t ws_size,
                              hipStream_t stream) {
    const float* x = (const float*)d_in[0];
    const float* w1 = (const float*)d_in[1];
    const float* b1 = (const float*)d_in[2];
    const float* w2 = (const float*)d_in[3];
    const float* b2 = (const float*)d_in[4];
    float* out = (float*)d_out;
    float* ws = (float*)d_ws;

    float* xn = ws;
    float* A = ws + 1048576;
    float* z = ws + 5242880;
    float* xc = ws + 22020096;
    float* part = z;  // reused after conv2(b) has consumed z, before conv1(b+1)

    norm_kernel<<<dim3(4, NBATCH), 256, 0, stream>>>(x, xn);
    aff_kernel<<<dim3(16, 16, NBATCH), 256, 0, stream>>>(xn, A);
    for (int b = 0; b < NBATCH; ++b) {
        conv1_kernel<<<1024, 512, 0, stream>>>(A, w1, b1, z, b);
        conv2_kernel<<<1024, 256, 0, stream>>>(z, w2, b2, xc);
        topk1_kernel<<<dim3(4, 8), 256, 0, stream>>>(xc, part);
        topk2_kernel<<<4, 256, 0, stream>>>(part, out, b);
    }
}

// Round 3
// 669.145 us; speedup vs baseline: 2.3852x; 2.3615x over previous
//
#include <hip/hip_runtime.h>

#define HW 1024
#define CCH 256
#define NBATCH 4

// ws layout (floats):
//   xn: [4][256][1024]        off 0         1,048,576
//   A : [4][1024][1024]       off 1048576   4,194,304
//   z : [16][1024][1024]      off 5242880  16,777,216   (per-batch reuse; topk
//                                                        partials also live here)
//   xc: [1024][1024]          off 22020096  1,048,576   (per-batch reuse)

__global__ __launch_bounds__(256) void norm_kernel(const float* __restrict__ x,
                                                   float* __restrict__ xn) {
    int b = blockIdx.y;
    int p = blockIdx.x * 256 + threadIdx.x;
    const float* xb = x + (size_t)b * CCH * HW;
    float* xnb = xn + (size_t)b * CCH * HW;
    float ss = 0.f;
#pragma unroll 8
    for (int c = 0; c < CCH; ++c) { float v = xb[c * HW + p]; ss += v * v; }
    float inv = 1.0f / fmaxf(sqrtf(ss), 1e-12f);
#pragma unroll 8
    for (int c = 0; c < CCH; ++c) xnb[c * HW + p] = xb[c * HW + p] * inv;
}

// A[b][p][m] = g(p,m) * sum_c xn[b][c][p] * xn[b][c][m]
__global__ __launch_bounds__(256) void aff_kernel(const float* __restrict__ xn,
                                                  float* __restrict__ Aout) {
    int b = blockIdx.z;
    int p0 = blockIdx.y * 64;
    int m0 = blockIdx.x * 64;
    const float* X = xn + (size_t)b * CCH * HW;
    __shared__ float As[16][64];
    __shared__ float Bs[16][64];
    int tid = threadIdx.x;
    int ty = tid >> 4, tx = tid & 15;
    float acc[4][4] = {};
    for (int kk = 0; kk < CCH; kk += 16) {
        int lr = tid >> 4;
        int lc4 = (tid & 15) * 4;
        *(float4*)&As[lr][lc4] = *(const float4*)&X[(size_t)(kk + lr) * HW + p0 + lc4];
        *(float4*)&Bs[lr][lc4] = *(const float4*)&X[(size_t)(kk + lr) * HW + m0 + lc4];
        __syncthreads();
#pragma unroll
        for (int k = 0; k < 16; ++k) {
            float4 av = *(float4*)&As[k][ty * 4];
            float4 bv = *(float4*)&Bs[k][tx * 4];
            float aa[4] = {av.x, av.y, av.z, av.w};
            float bb[4] = {bv.x, bv.y, bv.z, bv.w};
#pragma unroll
            for (int i = 0; i < 4; ++i)
#pragma unroll
                for (int j = 0; j < 4; ++j) acc[i][j] += aa[i] * bb[j];
        }
        __syncthreads();
    }
#pragma unroll
    for (int i = 0; i < 4; ++i) {
        int p = p0 + ty * 4 + i;
        int prr = p >> 5, pcc = p & 31;
        float res[4];
#pragma unroll
        for (int j = 0; j < 4; ++j) {
            int m = m0 + tx * 4 + j;
            int dr = (m >> 5) - prr;
            int dc = (m & 31) - pcc;
            float gg = 1.0f - __expf(-(float)(dr * dr + dc * dc) * 0.1953125f);
            res[j] = acc[i][j] * gg;
        }
        *(float4*)&Aout[((size_t)b * HW + p) * HW + m0 + tx * 4] =
            make_float4(res[0], res[1], res[2], res[3]);
    }
}

// conv1: z[ch][P][Q] = sum_{i,j,u,v} w1[ch,0,i,j,u,v] * A[b][P+(i-1,j-1)][Q+(u-1,v-1)]
//                      + bias1(r1,ch).   512 threads: 2 Q-pixels x 16 ch each.
__global__ __launch_bounds__(512) void conv1_kernel(const float* __restrict__ A,
                                                    const float* __restrict__ w1,
                                                    const float* __restrict__ b1,
                                                    float* __restrict__ z, int b) {
    __shared__ float At[9][34 * 34];
    __shared__ float w1s[1296];  // transposed: [tap(81)][ch(16)]
    int tid = threadIdx.x;
    int P = blockIdx.x;
    int r1 = P >> 5, c1 = P & 31;

    // batch-load all staging data into regs first (no load->ds_write chains)
    float2 va[9];
#pragma unroll
    for (int nb = 0; nb < 9; ++nb) {
        int r1p = r1 + nb / 3 - 1, c1p = c1 + nb % 3 - 1;
        va[nb] = make_float2(0.f, 0.f);
        if (((unsigned)r1p < 32u) && ((unsigned)c1p < 32u))
            va[nb] = ((const float2*)(A + ((size_t)b * HW + r1p * 32 + c1p) * HW))[tid];
    }

    for (int i = tid; i < 1296; i += 512) {
        int ch = i / 81;
        int off = i - ch * 81;
        w1s[off * 16 + ch] = w1[i];
    }
    for (int i = tid; i < 9 * 34 * 34; i += 512) ((float*)At)[i] = 0.f;
    __syncthreads();
    {
        int qr = tid >> 4, qc = (tid & 15) * 2;
#pragma unroll
        for (int nb = 0; nb < 9; ++nb) {
            At[nb][(qr + 1) * 34 + qc + 1] = va[nb].x;
            At[nb][(qr + 1) * 34 + qc + 2] = va[nb].y;
        }
    }
    __syncthreads();

    int c2 = tid & 31, r2g = tid >> 5;  // rows r2g and r2g+16
    float acc[16][2] = {};
    for (int nb = 0; nb < 9; ++nb) {
        const float* Ap = At[nb];
        int wb = (nb / 3) * 27 + (nb % 3) * 9;
#pragma unroll
        for (int u = 0; u < 3; ++u)
#pragma unroll
            for (int v = 0; v < 3; ++v) {
                int off = wb + u * 3 + v;
                float a0 = Ap[(r2g + u) * 34 + c2 + v];
                float a1 = Ap[(r2g + 16 + u) * 34 + c2 + v];
#pragma unroll
                for (int cg = 0; cg < 4; ++cg) {
                    float4 wv = *(const float4*)&w1s[off * 16 + cg * 4];
                    float wa[4] = {wv.x, wv.y, wv.z, wv.w};
#pragma unroll
                    for (int cc = 0; cc < 4; ++cc) {
                        acc[cg * 4 + cc][0] += wa[cc] * a0;
                        acc[cg * 4 + cc][1] += wa[cc] * a1;
                    }
                }
            }
    }

#pragma unroll
    for (int ch = 0; ch < 16; ++ch) {
        float bias = b1[16 + ch];
        if (r1 >= 1) bias += b1[ch];
        if (r1 <= 30) bias += b1[32 + ch];
        float* zp = z + ((size_t)ch * HW + P) * HW;
        zp[tid] = acc[ch][0] + bias;
        zp[tid + 512] = acc[ch][1] + bias;
    }
}

// conv2: block = 128 threads handles P-pair (r1, c1b) and (r1, c1b+1).
// Stage 3x4 neighborhood (12 images) per channel with register-prefetch
// double buffering; each thread computes a 2x4 Q-tile for BOTH planes.
#define HSTR 36
#define IMSZ (34 * HSTR)  // 1224 words
__global__ __launch_bounds__(128) void conv2_kernel(const float* __restrict__ z,
                                                    const float* __restrict__ w2,
                                                    const float* __restrict__ b2,
                                                    float* __restrict__ xc) {
    __shared__ float hal[12 * IMSZ];  // 58,752 B
    __shared__ float w2s[1296];
    int tid = threadIdx.x;
    int blk = blockIdx.x;  // 512 blocks
    int r1 = blk >> 4;
    int c1b = (blk & 15) << 1;

    for (int i = tid; i < 1296; i += 128) w2s[i] = w2[i];
    for (int i = tid; i < 12 * IMSZ; i += 128) hal[i] = 0.f;

    // image img = dr*4+dc -> P = (r1-1+dr, c1b-1+dc); invalid images stay zero
    int ioff[12];
    bool ivalid[12];
#pragma unroll
    for (int img = 0; img < 12; ++img) {
        int pr = r1 - 1 + (img >> 2), pc = c1b - 1 + (img & 3);
        ivalid[img] = ((unsigned)pr < 32u) && ((unsigned)pc < 32u);
        ioff[img] = pr * 32 + pc;
    }

    // staging element map: thread stages float4 #tid and #(tid+128) of each image
    int qrA = tid >> 3, qcA = (tid & 7) << 2;           // elems tid*4..
    int qrB = qrA + 16, qcB = qcA;                      // elems (tid+128)*4..
    int wbA = (qrA + 1) * HSTR + qcA + 1;
    int wbB = (qrB + 1) * HSTR + qcB + 1;
    int a = (tid >> 3) & 3;  // bank-rotation amount

    float4 pfA[12], pfB[12];

#define LOADCH(CH)                                                            \
    {                                                                         \
        _Pragma("unroll") for (int img = 0; img < 12; ++img) {                \
            if (ivalid[img]) {                                                \
                const float4* s =                                             \
                    (const float4*)(z + ((size_t)(CH)*HW + ioff[img]) * HW);  \
                pfA[img] = s[tid];                                            \
                pfB[img] = s[tid + 128];                                      \
            }                                                                 \
        }                                                                     \
    }

    LOADCH(0);

    // compute tile: output rows 2*rg, 2*rg+1; cols 4*cg..4*cg+3 (both planes)
    int rg = tid >> 3;   // 0..15
    int cg = tid & 7;    // 0..7
    int rbase = 2 * rg * HSTR + 4 * cg;  // stored row 2rg = input qr 2rg-1; slot 4cg = qc 4cg-1

    float acc0[2][4] = {};
    float acc1[2][4] = {};

    for (int ch = 0; ch < 16; ++ch) {
        __syncthreads();  // previous compute done / init done
        // rotated scalar writes (bank-balanced)
#pragma unroll
        for (int img = 0; img < 12; ++img) {
            if (ivalid[img]) {
                float vA[4] = {pfA[img].x, pfA[img].y, pfA[img].z, pfA[img].w};
                float vB[4] = {pfB[img].x, pfB[img].y, pfB[img].z, pfB[img].w};
                // rotate by a via two conditional swaps (static indexing)
                float rA[4], rB[4];
                {
                    float t0 = (a & 1) ? vA[1] : vA[0], t1 = (a & 1) ? vA[2] : vA[1];
                    float t2 = (a & 1) ? vA[3] : vA[2], t3 = (a & 1) ? vA[0] : vA[3];
                    rA[0] = (a & 2) ? t2 : t0; rA[1] = (a & 2) ? t3 : t1;
                    rA[2] = (a & 2) ? t0 : t2; rA[3] = (a & 2) ? t1 : t3;
                    float s0 = (a & 1) ? vB[1] : vB[0], s1 = (a & 1) ? vB[2] : vB[1];
                    float s2 = (a & 1) ? vB[3] : vB[2], s3 = (a & 1) ? vB[0] : vB[3];
                    rB[0] = (a & 2) ? s2 : s0; rB[1] = (a & 2) ? s3 : s1;
                    rB[2] = (a & 2) ? s0 : s2; rB[3] = (a & 2) ? s1 : s3;
                }
                float* hb = &hal[img * IMSZ];
#pragma unroll
                for (int j = 0; j < 4; ++j) {
                    // lane writes slot k=(j+a)&3 with element k; rA[j] == elem (j+a)&3
                    int k0 = (j + a) & 3;
                    hb[wbA + k0] = rA[j];
                    hb[wbB + k0] = rB[j];
                }
            }
        }
        __syncthreads();
        if (ch < 15) LOADCH(ch + 1);  // prefetch next channel under compute

        // compute
#pragma unroll
        for (int img = 0; img < 12; ++img) {
            int dr = img >> 2, dc = img & 3;
            const float* base = &hal[img * IMSZ + rbase];
            float rv[4][6];
#pragma unroll
            for (int i = 0; i < 4; ++i) {
                float4 t4 = *(const float4*)(base + i * HSTR);
                float2 t2 = *(const float2*)(base + i * HSTR + 4);
                rv[i][0] = t4.x; rv[i][1] = t4.y; rv[i][2] = t4.z;
                rv[i][3] = t4.w; rv[i][4] = t2.x; rv[i][5] = t2.y;
            }
            if (dc <= 2) {  // plane 0, tap j = dc
                const float* wp = &w2s[ch * 81 + dr * 27 + dc * 9];
#pragma unroll
                for (int u = 0; u < 3; ++u)
#pragma unroll
                    for (int v = 0; v < 3; ++v) {
                        float w = wp[u * 3 + v];
#pragma unroll
                        for (int orr = 0; orr < 2; ++orr)
#pragma unroll
                            for (int oc = 0; oc < 4; ++oc)
                                acc0[orr][oc] += w * rv[orr + u][oc + v];
                    }
            }
            if (dc >= 1) {  // plane 1, tap j = dc-1
                const float* wp = &w2s[ch * 81 + dr * 27 + (dc - 1) * 9];
#pragma unroll
                for (int u = 0; u < 3; ++u)
#pragma unroll
                    for (int v = 0; v < 3; ++v) {
                        float w = wp[u * 3 + v];
#pragma unroll
                        for (int orr = 0; orr < 2; ++orr)
#pragma unroll
                            for (int oc = 0; oc < 4; ++oc)
                                acc1[orr][oc] += w * rv[orr + u][oc + v];
                    }
            }
        }
    }

    float bias = b2[1] + (r1 >= 1 ? b2[0] : 0.f) + (r1 <= 30 ? b2[2] : 0.f);
    int P0 = r1 * 32 + c1b;
#pragma unroll
    for (int orr = 0; orr < 2; ++orr) {
        int qoff = (2 * rg + orr) * 32 + 4 * cg;
        *(float4*)&xc[(size_t)P0 * HW + qoff] =
            make_float4(acc0[orr][0] + bias, acc0[orr][1] + bias,
                        acc0[orr][2] + bias, acc0[orr][3] + bias);
        *(float4*)&xc[(size_t)(P0 + 1) * HW + qoff] =
            make_float4(acc1[orr][0] + bias, acc1[orr][1] + bias,
                        acc1[orr][2] + bias, acc1[orr][3] + bias);
    }
#undef LOADCH
}

__device__ __forceinline__ void top3_push(float v, float& t0, float& t1, float& t2) {
    float n0 = fminf(t0, v);
    t0 = fmaxf(t0, v);
    float n1 = fminf(t1, n0);
    t1 = fmaxf(t1, n0);
    t2 = fmaxf(t2, n1);
}

// stage 1: block (qc, pc): top3 over 128 P-rows for 256 q columns
__global__ __launch_bounds__(256) void topk1_kernel(const float* __restrict__ xc,
                                                    float* __restrict__ part) {
    int q = blockIdx.x * 256 + threadIdx.x;
    int pc = blockIdx.y;
    float t0 = -1e30f, t1 = -1e30f, t2 = -1e30f;
    for (int p = pc * 128; p < pc * 128 + 128; ++p)
        top3_push(xc[(size_t)p * HW + q], t0, t1, t2);
    part[(size_t)(pc * 3 + 0) * HW + q] = t0;
    part[(size_t)(pc * 3 + 1) * HW + q] = t1;
    part[(size_t)(pc * 3 + 2) * HW + q] = t2;
}

__global__ __launch_bounds__(256) void topk2_kernel(const float* __restrict__ part,
                                                    float* __restrict__ out, int b) {
    int q = blockIdx.x * 256 + threadIdx.x;
    float t0 = -1e30f, t1 = -1e30f, t2 = -1e30f;
    for (int k = 0; k < 24; ++k) top3_push(part[(size_t)k * HW + q], t0, t1, t2);
    float* ob = out + (size_t)b * 3 * HW;
    ob[q] = t0;
    ob[HW + q] = t1;
    ob[2 * HW + q] = t2;
}

extern "C" void kernel_launch(void* const* d_in, const int* in_sizes, int n_in,
                              void* d_out, int out_size, void* d_ws, size_t ws_size,
                              hipStream_t stream) {
    const float* x = (const float*)d_in[0];
    const float* w1 = (const float*)d_in[1];
    const float* b1 = (const float*)d_in[2];
    const float* w2 = (const float*)d_in[3];
    const float* b2 = (const float*)d_in[4];
    float* out = (float*)d_out;
    float* ws = (float*)d_ws;

    float* xn = ws;
    float* A = ws + 1048576;
    float* z = ws + 5242880;
    float* xc = ws + 22020096;
    float* part = z;  // reused after conv2(b) consumed z, before conv1(b+1)

    norm_kernel<<<dim3(4, NBATCH), 256, 0, stream>>>(x, xn);
    aff_kernel<<<dim3(16, 16, NBATCH), 256, 0, stream>>>(xn, A);
    for (int b = 0; b < NBATCH; ++b) {
        conv1_kernel<<<1024, 512, 0, stream>>>(A, w1, b1, z, b);
        conv2_kernel<<<512, 128, 0, stream>>>(z, w2, b2, xc);
        topk1_kernel<<<dim3(4, 8), 256, 0, stream>>>(xc, part);
        topk2_kernel<<<4, 256, 0, stream>>>(part, out, b);
    }
}

// Round 4
// 425.584 us; speedup vs baseline: 3.7503x; 1.5723x over previous
//
#include <hip/hip_runtime.h>

#define HW 1024
#define CCH 256

// ws layout (float32 units), total 23,068,672 floats = 92.27 MB (== round-1 footprint):
//   xn  : f32   [4][256][1024]        off 0           1,048,576
//   Abf : bf16  [4][1024][1024]       off 1,048,576   2,097,152 (f32 units)
//   z2  : bf16  [2][16][1024][1024]   off 3,145,728  16,777,216
//   xc2 : f32   [2][1024][1024]       off 19,922,944  2,097,152
//   part: f32   [2][8][3][1024]       off 22,020,096     49,152

__device__ __forceinline__ unsigned short f2bf(float f) {
    unsigned u = __float_as_uint(f);
    u += 0x7fffu + ((u >> 16) & 1u);
    return (unsigned short)(u >> 16);
}
__device__ __forceinline__ float bflo(unsigned d) { return __uint_as_float(d << 16); }
__device__ __forceinline__ float bfhi(unsigned d) { return __uint_as_float(d & 0xffff0000u); }

__global__ __launch_bounds__(256) void norm_kernel(const float* __restrict__ x,
                                                   float* __restrict__ xn) {
    int b = blockIdx.y;
    int p = blockIdx.x * 256 + threadIdx.x;
    const float* xb = x + (size_t)b * CCH * HW;
    float* xnb = xn + (size_t)b * CCH * HW;
    float ss = 0.f;
#pragma unroll 8
    for (int c = 0; c < CCH; ++c) { float v = xb[c * HW + p]; ss += v * v; }
    float inv = 1.0f / fmaxf(sqrtf(ss), 1e-12f);
#pragma unroll 8
    for (int c = 0; c < CCH; ++c) xnb[c * HW + p] = xb[c * HW + p] * inv;
}

// A[b][p][m] = g(p,m) * sum_c xn[b][c][p] * xn[b][c][m]  -> bf16
__global__ __launch_bounds__(256) void aff_kernel(const float* __restrict__ xn,
                                                  unsigned short* __restrict__ Abf) {
    int b = blockIdx.z;
    int p0 = blockIdx.y * 64;
    int m0 = blockIdx.x * 64;
    const float* X = xn + (size_t)b * CCH * HW;
    __shared__ float As[16][64];
    __shared__ float Bs[16][64];
    int tid = threadIdx.x;
    int ty = tid >> 4, tx = tid & 15;
    float acc[4][4] = {};
    for (int kk = 0; kk < CCH; kk += 16) {
        int lr = tid >> 4;
        int lc4 = (tid & 15) * 4;
        *(float4*)&As[lr][lc4] = *(const float4*)&X[(size_t)(kk + lr) * HW + p0 + lc4];
        *(float4*)&Bs[lr][lc4] = *(const float4*)&X[(size_t)(kk + lr) * HW + m0 + lc4];
        __syncthreads();
#pragma unroll
        for (int k = 0; k < 16; ++k) {
            float4 av = *(float4*)&As[k][ty * 4];
            float4 bv = *(float4*)&Bs[k][tx * 4];
            float aa[4] = {av.x, av.y, av.z, av.w};
            float bb[4] = {bv.x, bv.y, bv.z, bv.w};
#pragma unroll
            for (int i = 0; i < 4; ++i)
#pragma unroll
                for (int j = 0; j < 4; ++j) acc[i][j] += aa[i] * bb[j];
        }
        __syncthreads();
    }
#pragma unroll
    for (int i = 0; i < 4; ++i) {
        int p = p0 + ty * 4 + i;
        int prr = p >> 5, pcc = p & 31;
        ushort4 res;
        unsigned short* rp = &res.x;
#pragma unroll
        for (int j = 0; j < 4; ++j) {
            int m = m0 + tx * 4 + j;
            int dr = (m >> 5) - prr;
            int dc = (m & 31) - pcc;
            float gg = 1.0f - __expf(-(float)(dr * dr + dc * dc) * 0.1953125f);
            rp[j] = f2bf(acc[i][j] * gg);
        }
        *(ushort4*)&Abf[((size_t)b * HW + p) * HW + m0 + tx * 4] = res;
    }
}

// conv1: z[bi][ch][P][Q] = conv(A) + bias1(r1,ch), output bf16. One block per (P, bi).
__global__ __launch_bounds__(512) void conv1_kernel(const unsigned short* __restrict__ Abf,
                                                    const float* __restrict__ w1,
                                                    const float* __restrict__ b1,
                                                    unsigned short* __restrict__ z2,
                                                    int pair) {
    __shared__ float At[9][34 * 34];
    __shared__ float w1s[1296];  // [tap(81)][ch(16)]
    int tid = threadIdx.x;
    int P = blockIdx.x;
    int bi = blockIdx.y;
    int b = pair * 2 + bi;
    int r1 = P >> 5, c1 = P & 31;

    unsigned va[9];
#pragma unroll
    for (int nb = 0; nb < 9; ++nb) {
        int r1p = r1 + nb / 3 - 1, c1p = c1 + nb % 3 - 1;
        va[nb] = 0u;
        if (((unsigned)r1p < 32u) && ((unsigned)c1p < 32u))
            va[nb] = ((const unsigned*)(Abf + ((size_t)b * HW + r1p * 32 + c1p) * HW))[tid];
    }

    for (int i = tid; i < 1296; i += 512) {
        int ch = i / 81;
        int off = i - ch * 81;
        w1s[off * 16 + ch] = w1[i];
    }
    for (int i = tid; i < 9 * 34 * 34; i += 512) ((float*)At)[i] = 0.f;
    __syncthreads();
    {
        int qr = tid >> 4, qc = (tid & 15) * 2;
#pragma unroll
        for (int nb = 0; nb < 9; ++nb) {
            At[nb][(qr + 1) * 34 + qc + 1] = bflo(va[nb]);
            At[nb][(qr + 1) * 34 + qc + 2] = bfhi(va[nb]);
        }
    }
    __syncthreads();

    int c2 = tid & 31, r2g = tid >> 5;  // q pixels tid, tid+512
    float acc[16][2] = {};
    for (int nb = 0; nb < 9; ++nb) {
        const float* Ap = At[nb];
        int wb = (nb / 3) * 27 + (nb % 3) * 9;
#pragma unroll
        for (int u = 0; u < 3; ++u)
#pragma unroll
            for (int v = 0; v < 3; ++v) {
                int off = wb + u * 3 + v;
                float a0 = Ap[(r2g + u) * 34 + c2 + v];
                float a1 = Ap[(r2g + 16 + u) * 34 + c2 + v];
#pragma unroll
                for (int cg = 0; cg < 4; ++cg) {
                    float4 wv = *(const float4*)&w1s[off * 16 + cg * 4];
                    float wa[4] = {wv.x, wv.y, wv.z, wv.w};
#pragma unroll
                    for (int cc = 0; cc < 4; ++cc) {
                        acc[cg * 4 + cc][0] += wa[cc] * a0;
                        acc[cg * 4 + cc][1] += wa[cc] * a1;
                    }
                }
            }
    }

#pragma unroll
    for (int ch = 0; ch < 16; ++ch) {
        float bias = b1[16 + ch];
        if (r1 >= 1) bias += b1[ch];
        if (r1 <= 30) bias += b1[32 + ch];
        unsigned short* zp = z2 + (((size_t)bi * 16 + ch) * HW + P) * HW;
        zp[tid] = f2bf(acc[ch][0] + bias);
        zp[tid + 512] = f2bf(acc[ch][1] + bias);
    }
}

// conv2: block = 512 thr = 8 waves; block owns 2x4 P-planes, wave = one plane.
// 24 halo images (4x6) staged in bf16 LDS per channel, register-prefetched.
// Thread computes a 4x4 Q-tile of its wave's plane.
#define C2STR 36
#define C2IMG (34 * C2STR)  // 1224 ushorts
__global__ __launch_bounds__(512) void conv2_kernel(const unsigned short* __restrict__ z2,
                                                    const float* __restrict__ w2,
                                                    const float* __restrict__ b2,
                                                    float* __restrict__ xc2) {
    __shared__ unsigned short zh[24 * C2IMG];  // 58,752 B
    __shared__ float w2s[1296];
    int tid = threadIdx.x;
    int pb = blockIdx.x;  // 0..127
    int bi = blockIdx.y;  // batch in pair
    int pr0 = (pb >> 3) * 2, pc0 = (pb & 7) * 4;
    int w = tid >> 6;            // wave id 0..7
    int wr = w >> 2, wc = w & 3; // plane (pr0+wr, pc0+wc)
    int lane = tid & 63;
    int qtr = lane >> 3, qtc = lane & 7;

    for (int i = tid; i < 1296; i += 512) w2s[i] = w2[i];
    for (int i = tid; i < 24 * C2IMG; i += 512) zh[i] = 0;

    // wave stages imgs 3w..3w+2; lane stages elems [16*lane..16*lane+15] of each
    int simgP[3];
    bool svalid[3];
#pragma unroll
    for (int ii = 0; ii < 3; ++ii) {
        int img = 3 * w + ii;
        int dr = img / 6, dc = img % 6;
        int pr = pr0 - 1 + dr, pc = pc0 - 1 + dc;
        svalid[ii] = ((unsigned)pr < 32u) && ((unsigned)pc < 32u);
        simgP[ii] = pr * 32 + pc;
    }
    int srow = lane >> 1, scol = (lane & 1) * 16;
    int sbase[3];
#pragma unroll
    for (int ii = 0; ii < 3; ++ii)
        sbase[ii] = (3 * w + ii) * C2IMG + (srow + 1) * C2STR + scol + 2;

    uint4 pf[3][2];

#define C2_LOAD(CH)                                                                  \
    {                                                                                \
        _Pragma("unroll") for (int ii = 0; ii < 3; ++ii) {                           \
            if (svalid[ii]) {                                                        \
                const uint4* s = (const uint4*)(z2 + (((size_t)bi * 16 + (CH)) * HW  \
                                                     + simgP[ii]) * HW + 16 * lane); \
                pf[ii][0] = s[0];                                                    \
                pf[ii][1] = s[1];                                                    \
            }                                                                        \
        }                                                                            \
    }

    C2_LOAD(0);

    float acc[4][4] = {};

    for (int ch = 0; ch < 16; ++ch) {
        __syncthreads();  // previous compute / zero-init done
#pragma unroll
        for (int ii = 0; ii < 3; ++ii) {
            if (svalid[ii]) {
#pragma unroll
                for (int k = 0; k < 2; ++k) {
                    uint4 u = pf[ii][k];
                    int e = sbase[ii] + 8 * k;
                    *(unsigned*)&zh[e] = u.x;
                    *(unsigned*)&zh[e + 2] = u.y;
                    *(unsigned*)&zh[e + 4] = u.z;
                    *(unsigned*)&zh[e + 6] = u.w;
                }
            }
        }
        __syncthreads();
        if (ch < 15) C2_LOAD(ch + 1);

#pragma unroll
        for (int dri = 0; dri < 3; ++dri)
#pragma unroll
            for (int dci = 0; dci < 3; ++dci) {
                int img = (wr + dri) * 6 + (wc + dci);
                const unsigned short* ib = &zh[img * C2IMG];
                float rv[6][8];
#pragma unroll
                for (int i = 0; i < 6; ++i) {
                    uint2 a = *(const uint2*)&ib[(4 * qtr + i) * C2STR + 4 * qtc];
                    uint2 bq = *(const uint2*)&ib[(4 * qtr + i) * C2STR + 4 * qtc + 4];
                    rv[i][0] = bflo(a.x); rv[i][1] = bfhi(a.x);
                    rv[i][2] = bflo(a.y); rv[i][3] = bfhi(a.y);
                    rv[i][4] = bflo(bq.x); rv[i][5] = bfhi(bq.x);
                    rv[i][6] = bflo(bq.y); rv[i][7] = bfhi(bq.y);
                }
                const float* wp = &w2s[ch * 81 + dri * 27 + dci * 9];
                float w9[9];
#pragma unroll
                for (int t = 0; t < 9; ++t) w9[t] = wp[t];
#pragma unroll
                for (int u = 0; u < 3; ++u)
#pragma unroll
                    for (int v = 0; v < 3; ++v)
#pragma unroll
                        for (int j = 0; j < 4; ++j)
#pragma unroll
                            for (int k = 0; k < 4; ++k)
                                acc[j][k] += w9[u * 3 + v] * rv[j + u][k + v + 1];
            }
    }

    int r1 = pr0 + wr, c1 = pc0 + wc;
    float bias = b2[1] + (r1 >= 1 ? b2[0] : 0.f) + (r1 <= 30 ? b2[2] : 0.f);
    float* xp = xc2 + ((size_t)bi * HW + r1 * 32 + c1) * HW;
#pragma unroll
    for (int j = 0; j < 4; ++j) {
        *(float4*)&xp[(4 * qtr + j) * 32 + 4 * qtc] =
            make_float4(acc[j][0] + bias, acc[j][1] + bias,
                        acc[j][2] + bias, acc[j][3] + bias);
    }
#undef C2_LOAD
}

__device__ __forceinline__ void top3_push(float v, float& t0, float& t1, float& t2) {
    float n0 = fminf(t0, v);
    t0 = fmaxf(t0, v);
    float n1 = fminf(t1, n0);
    t1 = fmaxf(t1, n0);
    t2 = fmaxf(t2, n1);
}

__global__ __launch_bounds__(256) void topk1_kernel(const float* __restrict__ xc2,
                                                    float* __restrict__ part) {
    int q = blockIdx.x * 256 + threadIdx.x;
    int pc = blockIdx.y;
    int bi = blockIdx.z;
    float t0 = -1e30f, t1 = -1e30f, t2 = -1e30f;
    const float* xp = xc2 + (size_t)bi * HW * HW;
    for (int p = pc * 128; p < pc * 128 + 128; ++p)
        top3_push(xp[(size_t)p * HW + q], t0, t1, t2);
    float* pp = part + (size_t)(bi * 8 + pc) * 3 * HW;
    pp[q] = t0;
    pp[HW + q] = t1;
    pp[2 * HW + q] = t2;
}

__global__ __launch_bounds__(256) void topk2_kernel(const float* __restrict__ part,
                                                    float* __restrict__ out, int pair) {
    int q = blockIdx.x * 256 + threadIdx.x;
    int bi = blockIdx.y;
    float t0 = -1e30f, t1 = -1e30f, t2 = -1e30f;
    const float* pp = part + (size_t)bi * 24 * HW;
    for (int k = 0; k < 24; ++k) top3_push(pp[(size_t)k * HW + q], t0, t1, t2);
    float* ob = out + (size_t)(pair * 2 + bi) * 3 * HW;
    ob[q] = t0;
    ob[HW + q] = t1;
    ob[2 * HW + q] = t2;
}

extern "C" void kernel_launch(void* const* d_in, const int* in_sizes, int n_in,
                              void* d_out, int out_size, void* d_ws, size_t ws_size,
                              hipStream_t stream) {
    const float* x = (const float*)d_in[0];
    const float* w1 = (const float*)d_in[1];
    const float* b1 = (const float*)d_in[2];
    const float* w2 = (const float*)d_in[3];
    const float* b2 = (const float*)d_in[4];
    float* out = (float*)d_out;
    float* ws = (float*)d_ws;

    float* xn = ws;
    unsigned short* Abf = (unsigned short*)(ws + 1048576);
    unsigned short* z2 = (unsigned short*)(ws + 3145728);
    float* xc2 = ws + 19922944;
    float* part = ws + 22020096;

    norm_kernel<<<dim3(4, 4), 256, 0, stream>>>(x, xn);
    aff_kernel<<<dim3(16, 16, 4), 256, 0, stream>>>(xn, Abf);
    for (int pair = 0; pair < 2; ++pair) {
        conv1_kernel<<<dim3(1024, 2), 512, 0, stream>>>(Abf, w1, b1, z2, pair);
        conv2_kernel<<<dim3(128, 2), 512, 0, stream>>>(z2, w2, b2, xc2);
        topk1_kernel<<<dim3(4, 8, 2), 256, 0, stream>>>(xc2, part);
        topk2_kernel<<<dim3(4, 2), 256, 0, stream>>>(part, out, pair);
    }
}

// Round 5
// 383.830 us; speedup vs baseline: 4.1582x; 1.1088x over previous
//
#include <hip/hip_runtime.h>

#define HW 1024
#define CCH 256

// ws layout (f32 units):
//   xnT : bf16 [4][1024][256]       off 0            524,288
//   Af16: f16  [4][1024][1024]      off 524,288    2,097,152
//   z2  : f16  [2][16][1024][1024]  off 2,621,440 16,777,216
//   xc2 : f32  [2][1024][1024]      off 19,398,656 2,097,152
//   part: f32  [2][8][3][1024]      off 21,495,808    49,152
// total 21,544,960 floats = 86.2 MB

typedef _Float16 h2v __attribute__((ext_vector_type(2)));
typedef short bf16x8 __attribute__((ext_vector_type(8)));
typedef float f32x4 __attribute__((ext_vector_type(4)));

__device__ __forceinline__ float fdot2(unsigned a, unsigned b, float c) {
#if __has_builtin(__builtin_amdgcn_fdot2)
    return __builtin_amdgcn_fdot2(__builtin_bit_cast(h2v, a),
                                  __builtin_bit_cast(h2v, b), c, false);
#else
    h2v ha = __builtin_bit_cast(h2v, a), hb = __builtin_bit_cast(h2v, b);
    return c + (float)ha.x * (float)hb.x + (float)ha.y * (float)hb.y;
#endif
}
__device__ __forceinline__ unsigned packh2(float x, float y) {
    h2v h;
    h.x = (_Float16)x;
    h.y = (_Float16)y;
    return __builtin_bit_cast(unsigned, h);
}
__device__ __forceinline__ unsigned short f2bf(float f) {
    unsigned u = __float_as_uint(f);
    u += 0x7fffu + ((u >> 16) & 1u);
    return (unsigned short)(u >> 16);
}

// ---- norm: xnT[b][p][c] = bf16( x[b][c][p] / ||x[b][:][p]|| )
__global__ __launch_bounds__(256) void norm_kernel(const float* __restrict__ x,
                                                   unsigned short* __restrict__ xnT) {
    int b = blockIdx.y;
    int p = blockIdx.x * 256 + threadIdx.x;
    const float* xb = x + (size_t)b * CCH * HW;
    float ss = 0.f;
#pragma unroll 8
    for (int c = 0; c < CCH; ++c) { float v = xb[c * HW + p]; ss += v * v; }
    float inv = 1.0f / fmaxf(sqrtf(ss), 1e-12f);
    unsigned* o = (unsigned*)(xnT + ((size_t)b * HW + p) * CCH);
#pragma unroll 4
    for (int c = 0; c < CCH; c += 2) {
        unsigned lo = f2bf(xb[c * HW + p] * inv);
        unsigned hi = f2bf(xb[(c + 1) * HW + p] * inv);
        o[c >> 1] = lo | (hi << 16);
    }
}

// ---- aff (bf16 MFMA): Af16[b][p][m] = f16( g(p,m) * sum_c xnT[p][c]*xnT[m][c] )
__global__ __launch_bounds__(256) void aff_kernel(const unsigned short* __restrict__ xnT,
                                                  unsigned short* __restrict__ Af16) {
    int b = blockIdx.z;
    int p0 = blockIdx.y * 64, m0 = blockIdx.x * 64;
    const unsigned short* X = xnT + (size_t)b * HW * CCH;
    int lane = threadIdx.x & 63, w = threadIdx.x >> 6;
    int pw = p0 + (w >> 1) * 32, mw = m0 + (w & 1) * 32;
    int lr = lane & 15, lg = lane >> 4;
    f32x4 acc[2][2] = {};
    for (int ks = 0; ks < 8; ++ks) {
        int kc = ks * 32 + lg * 8;
        bf16x8 a0 = *(const bf16x8*)&X[(size_t)(pw + lr) * CCH + kc];
        bf16x8 a1 = *(const bf16x8*)&X[(size_t)(pw + 16 + lr) * CCH + kc];
        bf16x8 b0 = *(const bf16x8*)&X[(size_t)(mw + lr) * CCH + kc];
        bf16x8 b1 = *(const bf16x8*)&X[(size_t)(mw + 16 + lr) * CCH + kc];
        acc[0][0] = __builtin_amdgcn_mfma_f32_16x16x32_bf16(a0, b0, acc[0][0], 0, 0, 0);
        acc[0][1] = __builtin_amdgcn_mfma_f32_16x16x32_bf16(a0, b1, acc[0][1], 0, 0, 0);
        acc[1][0] = __builtin_amdgcn_mfma_f32_16x16x32_bf16(a1, b0, acc[1][0], 0, 0, 0);
        acc[1][1] = __builtin_amdgcn_mfma_f32_16x16x32_bf16(a1, b1, acc[1][1], 0, 0, 0);
    }
#pragma unroll
    for (int pi = 0; pi < 2; ++pi)
#pragma unroll
        for (int mi = 0; mi < 2; ++mi)
#pragma unroll
            for (int r = 0; r < 4; ++r) {
                int p = pw + 16 * pi + lg * 4 + r;
                int m = mw + 16 * mi + lr;
                int dr = (m >> 5) - (p >> 5);
                int dc = (m & 31) - (p & 31);
                float gg = 1.0f - __expf(-(float)(dr * dr + dc * dc) * 0.1953125f);
                float v = acc[pi][mi][r] * gg;
                Af16[((size_t)b * HW + p) * HW + m] =
                    __builtin_bit_cast(unsigned short, (_Float16)v);
            }
}

// ---- conv1: z[bi][ch][P][Q] (f16). Block per (P, bi); 512 thr: 1 row x 2 cols x 16ch.
__global__ __launch_bounds__(512, 2) void conv1_kernel(const unsigned short* __restrict__ Af16,
                                                       const float* __restrict__ w1,
                                                       const float* __restrict__ b1,
                                                       unsigned short* __restrict__ z2,
                                                       int pair) {
    __shared__ unsigned short At[9][34 * 40];  // f16, col c at slot c+2
    __shared__ unsigned w1p[864];              // [(nb*3+u)*2+kind][16ch] f16-pairs
    int tid = threadIdx.x;
    int P = blockIdx.x, bi = blockIdx.y, b = pair * 2 + bi;
    int r1 = P >> 5, c1 = P & 31;

    unsigned va[9];
#pragma unroll
    for (int nb = 0; nb < 9; ++nb) {
        int r1p = r1 + nb / 3 - 1, c1p = c1 + nb % 3 - 1;
        va[nb] = 0u;
        if (((unsigned)r1p < 32u) && ((unsigned)c1p < 32u))
            va[nb] = ((const unsigned*)(Af16 + ((size_t)b * HW + r1p * 32 + c1p) * HW))[tid];
    }
    for (int i = tid; i < 864; i += 512) {
        int ch = i & 15, kind = (i >> 4) & 1, rest = i >> 5;
        int u = rest % 3, nb = rest / 3;
        const float* wp = w1 + ch * 81 + nb * 9 + u * 3;
        w1p[i] = kind ? packh2(wp[2], 0.f) : packh2(wp[0], wp[1]);
    }
    for (int i = tid; i < 9 * 1360; i += 512) ((unsigned short*)At)[i] = 0;
    __syncthreads();
    {
        int wrow = tid >> 4, wslot = 2 * (tid & 15) + 2;
#pragma unroll
        for (int nb = 0; nb < 9; ++nb)
            *(unsigned*)&At[nb][(wrow + 1) * 40 + wslot] = va[nb];
    }
    __syncthreads();

    int orow = tid >> 4;  // 0..31
    int oc = tid & 15;    // out cols 2oc, 2oc+1
    int codd = oc & 1;
    int Bslot = 4 * (oc >> 1);
    float acc[16][2] = {};
    for (int nb = 0; nb < 9; ++nb) {
#pragma unroll
        for (int u = 0; u < 3; ++u) {
            const unsigned* rp = (const unsigned*)&At[nb][(orow + u) * 40 + Bslot];
            unsigned q0 = rp[0], q1 = rp[1], q2 = rp[2], q3 = rp[3];
            unsigned o0 = (q0 >> 16) | (q1 << 16);
            unsigned o1 = (q1 >> 16) | (q2 << 16);
            unsigned o2 = (q2 >> 16) | (q3 << 16);
            unsigned pa = codd ? o1 : o0, pb = codd ? o2 : o1;
            unsigned qa = codd ? q2 : q1, qb = codd ? q3 : q2;
            const unsigned* wb = &w1p[(nb * 3 + u) * 32];
#pragma unroll
            for (int cg = 0; cg < 4; ++cg) {
                uint4 w0 = *(const uint4*)&wb[cg * 4];
                uint4 w1v = *(const uint4*)&wb[16 + cg * 4];
                unsigned wa0[4] = {w0.x, w0.y, w0.z, w0.w};
                unsigned wa1[4] = {w1v.x, w1v.y, w1v.z, w1v.w};
#pragma unroll
                for (int cc = 0; cc < 4; ++cc) {
                    int ch = cg * 4 + cc;
                    acc[ch][0] = fdot2(wa0[cc], pa, acc[ch][0]);
                    acc[ch][0] = fdot2(wa1[cc], pb, acc[ch][0]);
                    acc[ch][1] = fdot2(wa0[cc], qa, acc[ch][1]);
                    acc[ch][1] = fdot2(wa1[cc], qb, acc[ch][1]);
                }
            }
        }
    }

#pragma unroll
    for (int ch = 0; ch < 16; ++ch) {
        float bias = b1[16 + ch];
        if (r1 >= 1) bias += b1[ch];
        if (r1 <= 30) bias += b1[32 + ch];
        unsigned pk = packh2(acc[ch][0] + bias, acc[ch][1] + bias);
        ((unsigned*)(z2 + (((size_t)bi * 16 + ch) * HW + P) * HW))[orow * 16 + oc] = pk;
    }
}

// ---- conv2: 256-thr block = 4 waves = 2x2 planes; 16 halo images f16, stride 40.
__global__ __launch_bounds__(256, 3) void conv2_kernel(const unsigned short* __restrict__ z2,
                                                       const float* __restrict__ w2,
                                                       const float* __restrict__ b2,
                                                       float* __restrict__ xc2) {
    __shared__ unsigned short zh[16][34 * 40];  // 43,520 B
    __shared__ unsigned w2p[864];
    int tid = threadIdx.x;
    int pb = blockIdx.x, bi = blockIdx.y;
    int pr0 = (pb >> 4) * 2, pc0 = (pb & 15) * 2;
    int w = tid >> 6, wr = w >> 1, wc = w & 1;
    int lane = tid & 63, qr = lane >> 3, qc = lane & 7;

    for (int i = tid; i < 864; i += 256) {
        int ch = i & 15, kind = (i >> 4) & 1, rest = i >> 5;
        int u = rest % 3, nb = rest / 3;
        const float* wp = w2 + ch * 81 + nb * 9 + u * 3;
        w2p[i] = kind ? packh2(wp[2], 0.f) : packh2(wp[0], wp[1]);
    }
    for (int i = tid; i < 16 * 1360; i += 256) ((unsigned short*)zh)[i] = 0;

    int ioff[16];
    bool iv[16];
#pragma unroll
    for (int g = 0; g < 16; ++g) {
        int pr = pr0 - 1 + (g >> 2), pc = pc0 - 1 + (g & 3);
        iv[g] = ((unsigned)pr < 32u) && ((unsigned)pc < 32u);
        ioff[g] = pr * 32 + pc;
    }
    int widx = ((tid >> 3) + 1) * 40 + 4 * (tid & 7) + 2;

    uint2 pf[16];
#define C2LOAD(CH)                                                                   \
    {                                                                                \
        _Pragma("unroll") for (int g = 0; g < 16; ++g) {                             \
            if (iv[g])                                                               \
                pf[g] = ((const uint2*)(z2 + (((size_t)bi * 16 + (CH)) * HW          \
                                              + ioff[g]) * HW))[tid];                \
        }                                                                            \
    }
    C2LOAD(0);

    float acc[4][4] = {};
#pragma unroll 1
    for (int ch = 0; ch < 16; ++ch) {
        __syncthreads();
#pragma unroll
        for (int g = 0; g < 16; ++g) {
            if (iv[g]) {
                unsigned* d = (unsigned*)&zh[g][widx];
                d[0] = pf[g].x;
                d[1] = pf[g].y;
            }
        }
        __syncthreads();
        if (ch < 15) C2LOAD(ch + 1);

#pragma unroll
        for (int dri = 0; dri < 3; ++dri)
#pragma unroll
            for (int dci = 0; dci < 3; ++dci) {
                int g = (wr + dri) * 4 + (wc + dci);
                const unsigned short* ib = zh[g];
                unsigned rU[6][4], rO[6][3];
#pragma unroll
                for (int rr = 0; rr < 6; ++rr) {
                    const unsigned* rp = (const unsigned*)&ib[(4 * qr + rr) * 40 + 4 * qc];
                    uint2 a = *(const uint2*)rp;
                    uint2 bq = *(const uint2*)(rp + 2);
                    rU[rr][0] = a.x; rU[rr][1] = a.y; rU[rr][2] = bq.x; rU[rr][3] = bq.y;
                    rO[rr][0] = (a.x >> 16) | (a.y << 16);
                    rO[rr][1] = (a.y >> 16) | (bq.x << 16);
                    rO[rr][2] = (bq.x >> 16) | (bq.y << 16);
                }
                int nb = dri * 3 + dci;
#pragma unroll
                for (int u = 0; u < 3; ++u) {
                    unsigned wk0 = w2p[((nb * 3 + u) * 2 + 0) * 16 + ch];
                    unsigned wk1 = w2p[((nb * 3 + u) * 2 + 1) * 16 + ch];
#pragma unroll
                    for (int j = 0; j < 4; ++j) {
                        int rr = j + u;
                        acc[j][0] = fdot2(wk0, rO[rr][0], acc[j][0]);
                        acc[j][0] = fdot2(wk1, rO[rr][1], acc[j][0]);
                        acc[j][1] = fdot2(wk0, rU[rr][1], acc[j][1]);
                        acc[j][1] = fdot2(wk1, rU[rr][2], acc[j][1]);
                        acc[j][2] = fdot2(wk0, rO[rr][1], acc[j][2]);
                        acc[j][2] = fdot2(wk1, rO[rr][2], acc[j][2]);
                        acc[j][3] = fdot2(wk0, rU[rr][2], acc[j][3]);
                        acc[j][3] = fdot2(wk1, rU[rr][3], acc[j][3]);
                    }
                }
            }
    }
#undef C2LOAD

    int r1 = pr0 + wr, c1 = pc0 + wc;
    float bias = b2[1] + (r1 >= 1 ? b2[0] : 0.f) + (r1 <= 30 ? b2[2] : 0.f);
    float* xp = xc2 + ((size_t)bi * HW + r1 * 32 + c1) * HW;
#pragma unroll
    for (int j = 0; j < 4; ++j)
        *(float4*)&xp[(4 * qr + j) * 32 + 4 * qc] =
            make_float4(acc[j][0] + bias, acc[j][1] + bias,
                        acc[j][2] + bias, acc[j][3] + bias);
}

__device__ __forceinline__ void top3_push(float v, float& t0, float& t1, float& t2) {
    float n0 = fminf(t0, v);
    t0 = fmaxf(t0, v);
    float n1 = fminf(t1, n0);
    t1 = fmaxf(t1, n0);
    t2 = fmaxf(t2, n1);
}

__global__ __launch_bounds__(256) void topk1_kernel(const float* __restrict__ xc2,
                                                    float* __restrict__ part) {
    int q = blockIdx.x * 256 + threadIdx.x;
    int pc = blockIdx.y, bi = blockIdx.z;
    float t0 = -1e30f, t1 = -1e30f, t2 = -1e30f;
    const float* xp = xc2 + (size_t)bi * HW * HW;
    for (int p = pc * 128; p < pc * 128 + 128; ++p)
        top3_push(xp[(size_t)p * HW + q], t0, t1, t2);
    float* pp = part + (size_t)(bi * 8 + pc) * 3 * HW;
    pp[q] = t0;
    pp[HW + q] = t1;
    pp[2 * HW + q] = t2;
}

__global__ __launch_bounds__(256) void topk2_kernel(const float* __restrict__ part,
                                                    float* __restrict__ out, int pair) {
    int q = blockIdx.x * 256 + threadIdx.x;
    int bi = blockIdx.y;
    float t0 = -1e30f, t1 = -1e30f, t2 = -1e30f;
    const float* pp = part + (size_t)bi * 24 * HW;
    for (int k = 0; k < 24; ++k) top3_push(pp[(size_t)k * HW + q], t0, t1, t2);
    float* ob = out + (size_t)(pair * 2 + bi) * 3 * HW;
    ob[q] = t0;
    ob[HW + q] = t1;
    ob[2 * HW + q] = t2;
}

extern "C" void kernel_launch(void* const* d_in, const int* in_sizes, int n_in,
                              void* d_out, int out_size, void* d_ws, size_t ws_size,
                              hipStream_t stream) {
    const float* x = (const float*)d_in[0];
    const float* w1 = (const float*)d_in[1];
    const float* b1 = (const float*)d_in[2];
    const float* w2 = (const float*)d_in[3];
    const float* b2 = (const float*)d_in[4];
    float* out = (float*)d_out;
    float* ws = (float*)d_ws;

    unsigned short* xnT = (unsigned short*)ws;
    unsigned short* Af16 = (unsigned short*)(ws + 524288);
    unsigned short* z2 = (unsigned short*)(ws + 2621440);
    float* xc2 = ws + 19398656;
    float* part = ws + 21495808;

    norm_kernel<<<dim3(4, 4), 256, 0, stream>>>(x, xnT);
    aff_kernel<<<dim3(16, 16, 4), 256, 0, stream>>>(xnT, Af16);
    for (int pair = 0; pair < 2; ++pair) {
        conv1_kernel<<<dim3(1024, 2), 512, 0, stream>>>(Af16, w1, b1, z2, pair);
        conv2_kernel<<<dim3(256, 2), 256, 0, stream>>>(z2, w2, b2, xc2);
        topk1_kernel<<<dim3(4, 8, 2), 256, 0, stream>>>(xc2, part);
        topk2_kernel<<<dim3(4, 2), 256, 0, stream>>>(part, out, pair);
    }
}

// Round 7
// 346.735 us; speedup vs baseline: 4.6031x; 1.1070x over previous
//
#include <hip/hip_runtime.h>

#define HW 1024
#define CCH 256

// ws layout (f32 units):
//   xnT : bf16 [4][1024][256]       off 0            524,288
//   Af16: f16  [4][1024][1024]      off 524,288    2,097,152
//   xc  : f32  [4][1024][1024]      off 2,621,440  4,194,304
//   Wpk : u32  [81][25][16]         off 6,815,744     32,400
//   BT  : f32  [32][3][3][3]        off 6,848,512        864
//   part: f32  [4][8][3][1024]      off 6,849,536     98,304

typedef _Float16 h2v __attribute__((ext_vector_type(2)));
typedef short bf16x8 __attribute__((ext_vector_type(8)));
typedef float f32x4 __attribute__((ext_vector_type(4)));

__device__ __forceinline__ float fdot2(unsigned a, unsigned b, float c) {
#if __has_builtin(__builtin_amdgcn_fdot2)
    return __builtin_amdgcn_fdot2(__builtin_bit_cast(h2v, a),
                                  __builtin_bit_cast(h2v, b), c, false);
#else
    h2v ha = __builtin_bit_cast(h2v, a), hb = __builtin_bit_cast(h2v, b);
    return c + (float)ha.x * (float)hb.x + (float)ha.y * (float)hb.y;
#endif
}
__device__ __forceinline__ unsigned packh2(float x, float y) {
    h2v h;
    h.x = (_Float16)x;
    h.y = (_Float16)y;
    return __builtin_bit_cast(unsigned, h);
}
__device__ __forceinline__ unsigned short f2bf(float f) {
    unsigned u = __float_as_uint(f);
    u += 0x7fffu + ((u >> 16) & 1u);
    return (unsigned short)(u >> 16);
}

// ---- norm: xnT[b][p][c] = bf16( x[b][c][p] / ||x[b][:][p]|| )
__global__ __launch_bounds__(256) void norm_kernel(const float* __restrict__ x,
                                                   unsigned short* __restrict__ xnT) {
    int b = blockIdx.y;
    int p = blockIdx.x * 256 + threadIdx.x;
    const float* xb = x + (size_t)b * CCH * HW;
    float ss = 0.f;
#pragma unroll 8
    for (int c = 0; c < CCH; ++c) { float v = xb[c * HW + p]; ss += v * v; }
    float inv = 1.0f / fmaxf(sqrtf(ss), 1e-12f);
    unsigned* o = (unsigned*)(xnT + ((size_t)b * HW + p) * CCH);
#pragma unroll 4
    for (int c = 0; c < CCH; c += 2) {
        unsigned lo = f2bf(xb[c * HW + p] * inv);
        unsigned hi = f2bf(xb[(c + 1) * HW + p] * inv);
        o[c >> 1] = lo | (hi << 16);
    }
}

// ---- aff (bf16 MFMA): Af16[b][p][m] = f16( g(p,m) * sum_c xnT[p][c]*xnT[m][c] )
__global__ __launch_bounds__(256) void aff_kernel(const unsigned short* __restrict__ xnT,
                                                  unsigned short* __restrict__ Af16) {
    int b = blockIdx.z;
    int p0 = blockIdx.y * 64, m0 = blockIdx.x * 64;
    const unsigned short* X = xnT + (size_t)b * HW * CCH;
    int lane = threadIdx.x & 63, w = threadIdx.x >> 6;
    int pw = p0 + (w >> 1) * 32, mw = m0 + (w & 1) * 32;
    int lr = lane & 15, lg = lane >> 4;
    f32x4 acc[2][2] = {};
    for (int ks = 0; ks < 8; ++ks) {
        int kc = ks * 32 + lg * 8;
        bf16x8 a0 = *(const bf16x8*)&X[(size_t)(pw + lr) * CCH + kc];
        bf16x8 a1 = *(const bf16x8*)&X[(size_t)(pw + 16 + lr) * CCH + kc];
        bf16x8 b0 = *(const bf16x8*)&X[(size_t)(mw + lr) * CCH + kc];
        bf16x8 b1 = *(const bf16x8*)&X[(size_t)(mw + 16 + lr) * CCH + kc];
        acc[0][0] = __builtin_amdgcn_mfma_f32_16x16x32_bf16(a0, b0, acc[0][0], 0, 0, 0);
        acc[0][1] = __builtin_amdgcn_mfma_f32_16x16x32_bf16(a0, b1, acc[0][1], 0, 0, 0);
        acc[1][0] = __builtin_amdgcn_mfma_f32_16x16x32_bf16(a1, b0, acc[1][0], 0, 0, 0);
        acc[1][1] = __builtin_amdgcn_mfma_f32_16x16x32_bf16(a1, b1, acc[1][1], 0, 0, 0);
    }
#pragma unroll
    for (int pi = 0; pi < 2; ++pi)
#pragma unroll
        for (int mi = 0; mi < 2; ++mi)
#pragma unroll
            for (int r = 0; r < 4; ++r) {
                int p = pw + 16 * pi + lg * 4 + r;
                int m = mw + 16 * mi + lr;
                int dr = (m >> 5) - (p >> 5);
                int dc = (m & 31) - (p & 31);
                float gg = 1.0f - __expf(-(float)(dr * dr + dc * dc) * 0.1953125f);
                float v = acc[pi][mi][r] * gg;
                Af16[((size_t)b * HW + p) * HW + m] =
                    __builtin_bit_cast(unsigned short, (_Float16)v);
            }
}

// ---- composed-weight precompute: Wpk[class 81][tp 25][16] f16-pair uints.
// class = ((r1c*3+c1c)*3+r2c)*3+c2c; per dim: lo(coord=0) drops t2=0, hi(=31) drops t2=2.
__global__ __launch_bounds__(128) void wcomp_kernel(const float* __restrict__ w1,
                                                    const float* __restrict__ w2,
                                                    unsigned* __restrict__ Wpk) {
    int cls = blockIdx.x;
    int t = threadIdx.x;
    if (t < 25) Wpk[cls * 400 + t * 16 + 15] = 0u;  // pad slot: never poison
    if (t >= 125) return;
    int a = t / 25, b_ = (t / 5) % 5, c = t % 5;  // sP_r, sP_c, sQ_r taps (0..4)
    int r1c = cls / 27, c1c = (cls / 9) % 3, r2c = (cls / 3) % 3, c2c = cls % 3;
    float W[5] = {};
#pragma unroll
    for (int d = 0; d < 5; ++d) {
        float s = 0.f;
        for (int i2 = 0; i2 < 3; ++i2) {
            if ((r1c == 0 && i2 == 0) || (r1c == 2 && i2 == 2)) continue;
            int i1 = a - i2;
            if (i1 < 0 || i1 > 2) continue;
            for (int j2 = 0; j2 < 3; ++j2) {
                if ((c1c == 0 && j2 == 0) || (c1c == 2 && j2 == 2)) continue;
                int j1 = b_ - j2;
                if (j1 < 0 || j1 > 2) continue;
                for (int u2 = 0; u2 < 3; ++u2) {
                    if ((r2c == 0 && u2 == 0) || (r2c == 2 && u2 == 2)) continue;
                    int u1 = c - u2;
                    if (u1 < 0 || u1 > 2) continue;
                    for (int v2 = 0; v2 < 3; ++v2) {
                        if ((c2c == 0 && v2 == 0) || (c2c == 2 && v2 == 2)) continue;
                        int v1 = d - v2;
                        if (v1 < 0 || v1 > 2) continue;
                        int o1 = i1 * 27 + j1 * 9 + u1 * 3 + v1;
                        int o2 = i2 * 27 + j2 * 9 + u2 * 3 + v2;
                        for (int ch = 0; ch < 16; ++ch)
                            s += w1[ch * 81 + o1] * w2[ch * 81 + o2];
                    }
                }
            }
        }
        W[d] = s;
    }
    unsigned* o = &Wpk[cls * 400 + (a * 5 + b_) * 16 + c * 3];
    o[0] = packh2(W[0], W[1]);
    o[1] = packh2(W[2], W[3]);
    o[2] = packh2(W[4], 0.f);
}

// ---- bias precompute: BT[r1][c1c][r2c][c2c] = bias2eff(r1) + conv2(bias1-field)
__global__ __launch_bounds__(256) void bt_kernel(const float* __restrict__ w2,
                                                 const float* __restrict__ b1,
                                                 const float* __restrict__ b2,
                                                 float* __restrict__ BT) {
    int i = blockIdx.x * 256 + threadIdx.x;
    if (i >= 864) return;
    int r1 = i / 27, c1c = (i / 9) % 3, r2c = (i / 3) % 3, c2c = i % 3;
    float s = b2[1] + (r1 >= 1 ? b2[0] : 0.f) + (r1 <= 30 ? b2[2] : 0.f);
    for (int i2 = 0; i2 < 3; ++i2) {
        int rr = r1 + i2 - 1;
        if (rr < 0 || rr > 31) continue;
        for (int j2 = 0; j2 < 3; ++j2) {
            if ((c1c == 0 && j2 == 0) || (c1c == 2 && j2 == 2)) continue;
            for (int u2 = 0; u2 < 3; ++u2) {
                if ((r2c == 0 && u2 == 0) || (r2c == 2 && u2 == 2)) continue;
                for (int v2 = 0; v2 < 3; ++v2) {
                    if ((c2c == 0 && v2 == 0) || (c2c == 2 && v2 == 2)) continue;
                    for (int ch = 0; ch < 16; ++ch) {
                        float be = b1[16 + ch] + (rr >= 1 ? b1[ch] : 0.f) +
                                   (rr <= 30 ? b1[32 + ch] : 0.f);
                        s += w2[ch * 81 + i2 * 27 + j2 * 9 + u2 * 3 + v2] * be;
                    }
                }
            }
        }
    }
    BT[i] = s;
}

// ---- composed conv: xc[b][P][q] = sum_{25 P-taps, 25 Q-taps} W5v[class] * A + BT.
__global__ __launch_bounds__(256) void convc_kernel(const unsigned short* __restrict__ Af16,
                                                    const unsigned* __restrict__ Wpk,
                                                    const float* __restrict__ BT,
                                                    float* __restrict__ xc) {
    __shared__ __align__(16) unsigned wlds[3600];  // 9 variants x 25 tp x 16
    __shared__ unsigned short halo[36 * 40];
    __shared__ float bts[9];
    int tid = threadIdx.x;
    int P = blockIdx.x, b = blockIdx.y;
    int r1 = P >> 5, c1 = P & 31;
    int r1c = (r1 == 0) ? 0 : (r1 == 31) ? 2 : 1;
    int c1c = (c1 == 0) ? 0 : (c1 == 31) ? 2 : 1;

    const unsigned* wsrc = Wpk + (size_t)(r1c * 3 + c1c) * 3600;
    for (int i = tid; i < 3600; i += 256) wlds[i] = wsrc[i];
    for (int i = tid; i < 36 * 40; i += 256) halo[i] = 0;
    if (tid < 9) bts[tid] = BT[r1 * 27 + c1c * 9 + tid];

    int qr = tid >> 3, qc = tid & 7;  // output row, col-group (4 cols)
    int r2c = (qr == 0) ? 0 : (qr == 31) ? 2 : 1;
    int vm = r2c * 3 + 1;
    int v0 = r2c * 3 + ((qc == 0) ? 0 : 1);
    int v3 = r2c * 3 + ((qc == 7) ? 2 : 1);

    int dstw = ((tid >> 3) + 2) * 20 + 2 * (tid & 7) + 1;  // dword idx into halo
    const uint2* Ab = (const uint2*)(Af16 + (size_t)b * HW * HW);

    float acc0 = 0.f, acc1 = 0.f, acc2 = 0.f, acc3 = 0.f;

    int pr0 = min(max(r1 - 2, 0), 31), pc0 = min(max(c1 - 2, 0), 31);
    uint2 pf = Ab[(size_t)(pr0 * 32 + pc0) * 256 + tid];  // plane = 256 uint2

    __syncthreads();  // wlds / halo-zero / bts ready

#pragma unroll 1
    for (int tp = 0; tp < 25; ++tp) {
        int tr = tp / 5, tc = tp - tr * 5;
        int apr = r1 + tr - 2, apc = c1 + tc - 2;
        bool valid = ((unsigned)apr < 32u) && ((unsigned)apc < 32u);
        uint2 cur = pf;
        if (tp < 24) {
            int t2 = tp + 1;
            int tr2 = t2 / 5, tc2 = t2 - tr2 * 5;
            int npr = min(max(r1 + tr2 - 2, 0), 31);
            int npc = min(max(c1 + tc2 - 2, 0), 31);
            pf = Ab[(size_t)(npr * 32 + npc) * 256 + tid];
        }
        if (!valid) continue;  // A zero outside (block-uniform branch)
        __syncthreads();       // prev compute done before overwrite
        ((unsigned*)halo)[dstw] = cur.x;
        ((unsigned*)halo)[dstw + 1] = cur.y;
        __syncthreads();

        unsigned wA[16], wM[16], wB[16];
        {
            const uint4* s0 = (const uint4*)&wlds[v0 * 400 + tp * 16];
            *(uint4*)&wA[0] = s0[0]; *(uint4*)&wA[4] = s0[1];
            *(uint4*)&wA[8] = s0[2]; *(uint4*)&wA[12] = s0[3];
            const uint4* sm = (const uint4*)&wlds[vm * 400 + tp * 16];
            *(uint4*)&wM[0] = sm[0]; *(uint4*)&wM[4] = sm[1];
            *(uint4*)&wM[8] = sm[2]; *(uint4*)&wM[12] = sm[3];
            const uint4* s3 = (const uint4*)&wlds[v3 * 400 + tp * 16];
            *(uint4*)&wB[0] = s3[0]; *(uint4*)&wB[4] = s3[1];
            *(uint4*)&wB[8] = s3[2]; *(uint4*)&wB[12] = s3[3];
        }
#pragma unroll
        for (int u = 0; u < 5; ++u) {
            const unsigned* dp = (const unsigned*)&halo[(qr + u) * 40 + 4 * qc];
            uint2 d01 = *(const uint2*)dp;
            uint2 d23 = *(const uint2*)(dp + 2);
            unsigned u4v = dp[4];
            unsigned u0 = d01.x, u1v = d01.y, u2v = d23.x, u3v = d23.y;
            unsigned o0 = (u0 >> 16) | (u1v << 16);
            unsigned o1 = (u1v >> 16) | (u2v << 16);
            unsigned o2 = (u2v >> 16) | (u3v << 16);
            unsigned o3 = (u3v >> 16) | (u4v << 16);
            acc0 = fdot2(wA[u * 3 + 0], u0, acc0);
            acc0 = fdot2(wA[u * 3 + 1], u1v, acc0);
            acc0 = fdot2(wA[u * 3 + 2], u2v, acc0);
            acc1 = fdot2(wM[u * 3 + 0], o0, acc1);
            acc1 = fdot2(wM[u * 3 + 1], o1, acc1);
            acc1 = fdot2(wM[u * 3 + 2], o2, acc1);
            acc2 = fdot2(wM[u * 3 + 0], u1v, acc2);
            acc2 = fdot2(wM[u * 3 + 1], u2v, acc2);
            acc2 = fdot2(wM[u * 3 + 2], u3v, acc2);
            acc3 = fdot2(wB[u * 3 + 0], o1, acc3);
            acc3 = fdot2(wB[u * 3 + 1], o2, acc3);
            acc3 = fdot2(wB[u * 3 + 2], o3, acc3);
        }
    }

    float4 res = make_float4(acc0 + bts[v0], acc1 + bts[vm],
                             acc2 + bts[vm], acc3 + bts[v3]);
    *(float4*)&xc[((size_t)b * HW + P) * HW + qr * 32 + 4 * qc] = res;
}

__device__ __forceinline__ void top3_push(float v, float& t0, float& t1, float& t2) {
    float n0 = fminf(t0, v);
    t0 = fmaxf(t0, v);
    float n1 = fminf(t1, n0);
    t1 = fmaxf(t1, n0);
    t2 = fmaxf(t2, n1);
}

__global__ __launch_bounds__(256) void topk1_kernel(const float* __restrict__ xc,
                                                    float* __restrict__ part) {
    int q = blockIdx.x * 256 + threadIdx.x;
    int pc = blockIdx.y, bi = blockIdx.z;
    float t0 = -1e30f, t1 = -1e30f, t2 = -1e30f;
    const float* xp = xc + (size_t)bi * HW * HW;
    for (int p = pc * 128; p < pc * 128 + 128; ++p)
        top3_push(xp[(size_t)p * HW + q], t0, t1, t2);
    float* pp = part + (size_t)(bi * 8 + pc) * 3 * HW;
    pp[q] = t0;
    pp[HW + q] = t1;
    pp[2 * HW + q] = t2;
}

__global__ __launch_bounds__(256) void topk2_kernel(const float* __restrict__ part,
                                                    float* __restrict__ out) {
    int q = blockIdx.x * 256 + threadIdx.x;
    int bi = blockIdx.y;
    float t0 = -1e30f, t1 = -1e30f, t2 = -1e30f;
    const float* pp = part + (size_t)bi * 24 * HW;
    for (int k = 0; k < 24; ++k) top3_push(pp[(size_t)k * HW + q], t0, t1, t2);
    float* ob = out + (size_t)bi * 3 * HW;
    ob[q] = t0;
    ob[HW + q] = t1;
    ob[2 * HW + q] = t2;
}

extern "C" void kernel_launch(void* const* d_in, const int* in_sizes, int n_in,
                              void* d_out, int out_size, void* d_ws, size_t ws_size,
                              hipStream_t stream) {
    const float* x = (const float*)d_in[0];
    const float* w1 = (const float*)d_in[1];
    const float* b1 = (const float*)d_in[2];
    const float* w2 = (const float*)d_in[3];
    const float* b2 = (const float*)d_in[4];
    float* out = (float*)d_out;
    float* ws = (float*)d_ws;

    unsigned short* xnT = (unsigned short*)ws;
    unsigned short* Af16 = (unsigned short*)(ws + 524288);
    float* xc = ws + 2621440;
    unsigned* Wpk = (unsigned*)(ws + 6815744);
    float* BT = ws + 6848512;
    float* part = ws + 6849536;

    norm_kernel<<<dim3(4, 4), 256, 0, stream>>>(x, xnT);
    aff_kernel<<<dim3(16, 16, 4), 256, 0, stream>>>(xnT, Af16);
    wcomp_kernel<<<81, 128, 0, stream>>>(w1, w2, Wpk);
    bt_kernel<<<4, 256, 0, stream>>>(w2, b1, b2, BT);
    convc_kernel<<<dim3(1024, 4), 256, 0, stream>>>(Af16, Wpk, BT, xc);
    topk1_kernel<<<dim3(4, 8, 4), 256, 0, stream>>>(xc, part);
    topk2_kernel<<<dim3(4, 4), 256, 0, stream>>>(part, out);
}